// Round 1
// baseline (1553.084 us; speedup 1.0000x reference)
//
#include <hip/hip_runtime.h>
#include <math.h>

#define TILE 16
#define HALO 18
#define NHALO (HALO * HALO)   // 324
#define BLK 384
#define IH 256
#define IW 256

// ws layout (floats): [0, 4096) kc[64][8][8]; [4096, 20480) w_outT[256][64]

__global__ void edffn_prep(const float* __restrict__ fftf,
                           const float* __restrict__ w_out,
                           float* __restrict__ ws) {
  int blk = blockIdx.x, t = threadIdx.x;
  if (blk < 64) {
    // k_c = irfft2 of the effective full-spectrum multiplier (real, symmetric)
    int a = t >> 3, bb = t & 7;
    const float c0 = 0.70710678118654752f;
    const float ctab[8] = {1.f, c0, 0.f, -c0, -1.f, -c0, 0.f, c0};
    const float* F = fftf + blk * 40;  // [8][5]
    float acc = 0.f;
    for (int k1 = 0; k1 < 8; ++k1)
      for (int k2 = 0; k2 < 8; ++k2) {
        float f = (k2 <= 4) ? F[k1 * 5 + k2] : F[((8 - k1) & 7) * 5 + (8 - k2)];
        acc += f * ctab[(k1 * a + k2 * bb) & 7];
      }
    ws[blk * 64 + t] = acc * (1.f / 64.f);
  } else {
    // transpose w_out [64][256] -> w_outT [256][64] for contiguous uniform loads
    int idx = (blk - 64) * 64 + t;  // 0..16383
    int c = idx >> 6, o = idx & 63;
    ws[4096 + c * 64 + o] = w_out[o * 256 + c];
  }
}

__global__ __launch_bounds__(BLK, 2) void edffn_main(
    const float* __restrict__ x, const float* __restrict__ w_in,
    const float* __restrict__ b_in, const float* __restrict__ w_dw,
    const float* __restrict__ b_dw, const float* __restrict__ b_out,
    const float* __restrict__ kc, const float* __restrict__ w_outT,
    float* __restrict__ out) {
  __shared__ float smem[256 * 65];  // union: h double-buffer (loop) / y transpose (slow epilogue)
  __shared__ int s_flag;
  float2* hb = reinterpret_cast<float2*>(smem);  // [2][NHALO] of {h1,h2}

  const int t = threadIdx.x;
  const int gx0 = blockIdx.x * TILE, gy0 = blockIdx.y * TILE;
  const int b = blockIdx.z;

  // Each thread t<324 owns one halo pixel; cache its 64 input channels in VGPRs.
  float xr[64];
  int inb = 0;
  if (t < NHALO) {
    int hy = t / HALO, hx = t - hy * HALO;
    int gy = gy0 + hy - 1, gx = gx0 + hx - 1;
    inb = (gy >= 0) & (gy < IH) & (gx >= 0) & (gx < IW);
    if (inb) {
      const float* xp = x + (size_t)b * 64 * IH * IW + (size_t)gy * IW + gx;
#pragma unroll
      for (int k = 0; k < 64; ++k) xr[k] = xp[(size_t)k * IH * IW];
    } else {
#pragma unroll
      for (int k = 0; k < 64; ++k) xr[k] = 0.f;
    }
  } else {
#pragma unroll
    for (int k = 0; k < 64; ++k) xr[k] = 0.f;
  }

  // Threads t<256 each own one output pixel: 64-channel accumulator in VGPRs.
  float yacc[64];
#pragma unroll
  for (int o = 0; o < 64; ++o) yacc[o] = 0.f;

  const int oy = t >> 4, ox = t & 15;

  for (int c = 0; c < 256; ++c) {
    if (t < NHALO) {
      const float* w1 = w_in + c * 64;          // uniform -> s_load
      const float* w2 = w_in + (c + 256) * 64;  // uniform -> s_load
      float h1 = b_in[c], h2 = b_in[c + 256];
#pragma unroll
      for (int k = 0; k < 64; ++k) {
        h1 = fmaf(w1[k], xr[k], h1);
        h2 = fmaf(w2[k], xr[k], h2);
      }
      if (!inb) { h1 = 0.f; h2 = 0.f; }  // dwconv SAME zero-pads h outside image
      hb[(c & 1) * NHALO + t] = make_float2(h1, h2);
    }
    __syncthreads();  // single barrier per c; double-buffered h
    if (t < 256) {
      const float* wd1 = w_dw + c * 9;
      const float* wd2 = w_dw + (c + 256) * 9;
      float a1 = b_dw[c], a2 = b_dw[c + 256];
      const float2* hrow = hb + (c & 1) * NHALO;
#pragma unroll
      for (int dy = 0; dy < 3; ++dy) {
#pragma unroll
        for (int dx = 0; dx < 3; ++dx) {
          float2 hv = hrow[(oy + dy) * HALO + (ox + dx)];
          a1 = fmaf(wd1[dy * 3 + dx], hv.x, a1);
          a2 = fmaf(wd2[dy * 3 + dx], hv.y, a2);
        }
      }
      // exact GELU(a1) * a2
      float g = 0.5f * a1 * (1.f + erff(a1 * 0.70710678118654752f)) * a2;
      const float* wo = w_outT + c * 64;  // uniform -> s_load
#pragma unroll
      for (int o = 0; o < 64; ++o) yacc[o] = fmaf(wo[o], g, yacc[o]);
    }
  }

  // bias + check whether every channel's spectral kernel is an exact delta
  int mydelta = 1;
  if (t < 256) {
#pragma unroll
    for (int o = 0; o < 64; ++o) yacc[o] += b_out[o];
    const float* kp = kc + (t >> 2) * 64;
    for (int j = 0; j < 64; ++j) {
      float e = (j == 0) ? 1.f : 0.f;
      mydelta &= (fabsf(kp[j] - e) <= 1e-5f) ? 1 : 0;
    }
  }
  if (t == 0) s_flag = 1;
  __syncthreads();  // also fences smem reuse below
  if (!mydelta) s_flag = 0;
  __syncthreads();

  if (s_flag) {  // identity filter: write y directly (taken for all-ones filter)
    if (t < 256) {
      float* op = out + ((size_t)(b * 64) * IH + (gy0 + oy)) * IW + gx0 + ox;
#pragma unroll
      for (int o = 0; o < 64; ++o) op[(size_t)o * IH * IW] = yacc[o];
    }
    return;
  }

  // General path: per-patch circular convolution with kc (correct for any filter)
  if (t < 256) {
    int q = ((oy >> 3) << 1) | (ox >> 3);
    int idx = ((oy & 7) << 3) | (ox & 7);
#pragma unroll
    for (int o = 0; o < 64; ++o) smem[(o * 4 + q) * 65 + idx] = yacc[o];
  }
  __syncthreads();
  if (t < 256) {
    const int o = t >> 2, q = t & 3;
    const float* row = smem + t * 65;  // this (channel, patch)'s 64 pixels
    const float* kp = kc + o * 64;
    int py = gy0 + ((q >> 1) << 3), px = gx0 + ((q & 1) << 3);
    float* op = out + ((size_t)(b * 64 + o) * IH + py) * IW + px;
    for (int i = 0; i < 8; ++i)
      for (int j = 0; j < 8; ++j) {
        float acc = 0.f;
        for (int a_ = 0; a_ < 8; ++a_)
          for (int b_ = 0; b_ < 8; ++b_)
            acc += kp[a_ * 8 + b_] * row[((i - a_) & 7) * 8 + ((j - b_) & 7)];
        op[i * IW + j] = acc;
      }
  }
}

extern "C" void kernel_launch(void* const* d_in, const int* in_sizes, int n_in,
                              void* d_out, int out_size, void* d_ws, size_t ws_size,
                              hipStream_t stream) {
  const float* x = (const float*)d_in[0];
  const float* w_in = (const float*)d_in[1];
  const float* b_in = (const float*)d_in[2];
  const float* w_dw = (const float*)d_in[3];
  const float* b_dw = (const float*)d_in[4];
  const float* w_out = (const float*)d_in[5];
  const float* b_out = (const float*)d_in[6];
  const float* fftf = (const float*)d_in[7];
  float* out = (float*)d_out;
  float* ws = (float*)d_ws;

  edffn_prep<<<320, 64, 0, stream>>>(fftf, w_out, ws);
  dim3 grid(IW / TILE, IH / TILE, 4);
  edffn_main<<<grid, BLK, 0, stream>>>(x, w_in, b_in, w_dw, b_dw, b_out,
                                       ws, ws + 4096, out);
}

// Round 2
// 184.047 us; speedup vs baseline: 8.4385x; 8.4385x over previous
//
#include <hip/hip_runtime.h>
#include <math.h>

typedef __attribute__((ext_vector_type(8))) short short8;
typedef __attribute__((ext_vector_type(4))) float f32x4;

#define TILE 16
#define IH 256
#define IW 256

// ws byte layout: [0,16384) kc f32[64][64]; [16384,81920) wsA frags ushort;
//                 [81920,114688) wsC frags ushort
#define WSA_OFF 16384
#define WSC_OFF 81920

__device__ __forceinline__ unsigned short f2bf(float f) {
  unsigned int u = __builtin_bit_cast(unsigned int, f);
  u = (u + 0x7FFFu + ((u >> 16) & 1u)) >> 16;
  return (unsigned short)u;
}
__device__ __forceinline__ float bflo(unsigned int v) {
  return __builtin_bit_cast(float, v << 16);
}
__device__ __forceinline__ float bfhi(unsigned int v) {
  return __builtin_bit_cast(float, v & 0xFFFF0000u);
}

__global__ void edffn_prep(const float* __restrict__ fftf,
                           const float* __restrict__ w_in,
                           const float* __restrict__ w_out,
                           float* __restrict__ ws) {
  int blk = blockIdx.x, t = threadIdx.x;
  if (blk < 64) {
    // kc = irfft2 of the (real, symmetric) full-spectrum multiplier
    int a = t >> 3, bb = t & 7;
    const float c0 = 0.70710678118654752f;
    const float ctab[8] = {1.f, c0, 0.f, -c0, -1.f, -c0, 0.f, c0};
    const float* F = fftf + blk * 40;  // [8][5]
    float acc = 0.f;
    for (int k1 = 0; k1 < 8; ++k1)
      for (int k2 = 0; k2 < 8; ++k2) {
        float f = (k2 <= 4) ? F[k1 * 5 + k2] : F[((8 - k1) & 7) * 5 + (8 - k2)];
        acc += f * ctab[(k1 * a + k2 * bb) & 7];
      }
    ws[blk * 64 + t] = acc * (1.f / 64.f);
  } else if (blk < 128) {
    // w_in A-fragments: [chunk q=0..15][s=0,1][ks=0,1][lane][8]
    int b2 = blk - 64;
    int q = b2 >> 2, s = (b2 >> 1) & 1, ks = b2 & 1;
    int row = (s ? 256 : 0) + q * 16 + (t & 15);
    unsigned short* dst =
        (unsigned short*)((unsigned char*)ws + WSA_OFF) + (((q * 2 + s) * 2 + ks) * 64 + t) * 8;
    for (int j = 0; j < 8; ++j) {
      int k = ks * 32 + (t >> 4) * 8 + j;
      dst[j] = f2bf(w_in[row * 64 + k]);
    }
  } else {
    // w_out A-fragments: [pair p=0..7][mtile=0..3][lane][8]
    int b3 = blk - 128;
    int p = b3 >> 2, mt = b3 & 3;
    int row = mt * 16 + (t & 15);
    unsigned short* dst =
        (unsigned short*)((unsigned char*)ws + WSC_OFF) + ((p * 4 + mt) * 64 + t) * 8;
    for (int j = 0; j < 8; ++j) {
      int k = p * 32 + (t >> 4) * 8 + j;
      dst[j] = f2bf(w_out[row * 256 + k]);
    }
  }
}

// LDS: H12 [16 c'][18 rows][20 ushort2] = 23040 B  @0
//      G   [256 px][40 ushort (granule-XOR-swizzled)] = 20480 B @23040
//      slow-path YS f32[32][260] = 33280 B overlays @0
__global__ __launch_bounds__(256, 2) void edffn_main(
    const float* __restrict__ x, const float* __restrict__ b_in,
    const float* __restrict__ w_dw, const float* __restrict__ b_dw,
    const float* __restrict__ b_out, const float* __restrict__ ws,
    float* __restrict__ out) {
  __shared__ __align__(16) unsigned char smem[43520];
  __shared__ int s_flag;
  const int t = threadIdx.x;
  const int lane = t & 63, wave = t >> 6;
  const int l15 = lane & 15, lg = lane >> 4;
  const int gx0 = blockIdx.x * TILE, gy0 = blockIdx.y * TILE;
  const int b = blockIdx.z;
  const unsigned short* wsA = (const unsigned short*)((const unsigned char*)ws + WSA_OFF);
  const unsigned short* wsC = (const unsigned short*)((const unsigned char*)ws + WSC_OFF);

  // ---- stage-A B-fragments (x halo, bf16) held in registers across all chunks ----
  short8 xf[6][2];
  int haddr[6], hval[6], hinb[6];
  const float* xb = x + (size_t)b * 64 * 65536;
#pragma unroll
  for (int i = 0; i < 6; ++i) {
    int nt = wave + 4 * i;  // wave0: 0,4,..,20 ; waves1-3: last invalid
    int n = nt * 16 + l15;
    int hy = n / 18;
    int hx = n - hy * 18;
    int gy = gy0 + hy - 1, gx = gx0 + hx - 1;
    int vnt = (nt < 21) & (n < 324);
    int inb = vnt & (gy >= 0) & (gy < IH) & (gx >= 0) & (gx < IW);
    haddr[i] = hy * 80 + hx * 4;
    hval[i] = vnt;
    hinb[i] = inb;
    int gyc = min(max(gy, 0), IH - 1), gxc = min(max(gx, 0), IW - 1);
    const float* xp = xb + (size_t)gyc * IW + gxc;
#pragma unroll
    for (int ks = 0; ks < 2; ++ks) {
#pragma unroll
      for (int j = 0; j < 8; ++j) {
        int k = ks * 32 + lg * 8 + j;
        unsigned short bf = f2bf(xp[(size_t)k * 65536]);
        xf[i][ks][j] = (short)(inb ? bf : (unsigned short)0);
      }
    }
  }

  f32x4 accY[16];
#pragma unroll
  for (int i = 0; i < 16; ++i) accY[i] = (f32x4){0.f, 0.f, 0.f, 0.f};

  for (int q = 0; q < 16; ++q) {
    // ---- stage A: H(64 halo-ch x 324 px) via MFMA ----
    short8 af[2][2];
#pragma unroll
    for (int s = 0; s < 2; ++s)
#pragma unroll
      for (int ks = 0; ks < 2; ++ks)
        af[s][ks] = *(const short8*)(wsA + (((q * 2 + s) * 2 + ks) * 64 + lane) * 8);
    float bin[2][4];
#pragma unroll
    for (int s = 0; s < 2; ++s)
#pragma unroll
      for (int r = 0; r < 4; ++r) bin[s][r] = b_in[(s ? 256 : 0) + q * 16 + lg * 4 + r];

#pragma unroll
    for (int i = 0; i < 6; ++i) {
      if (wave + 4 * i < 21) {  // wave-uniform
#pragma unroll
        for (int s = 0; s < 2; ++s) {
          f32x4 acc = {0.f, 0.f, 0.f, 0.f};
          acc = __builtin_amdgcn_mfma_f32_16x16x32_bf16(af[s][0], xf[i][0], acc, 0, 0, 0);
          acc = __builtin_amdgcn_mfma_f32_16x16x32_bf16(af[s][1], xf[i][1], acc, 0, 0, 0);
          if (hval[i]) {  // per-lane mask on writes only (MFMA stays convergent)
#pragma unroll
            for (int r = 0; r < 4; ++r) {
              float v = hinb[i] ? (acc[r] + bin[s][r]) : 0.f;  // SAME pad: h=0 outside image
              *(unsigned short*)(smem + (lg * 4 + r) * 1440 + haddr[i] + 2 * s) = f2bf(v);
            }
          }
        }
      }
    }
    __syncthreads();

    // ---- dwconv 3x3 + exact GELU gate (thread = (c', oy), row-wise) ----
    {
      const int cp = t >> 4, oy = t & 15;
      const int cg1 = q * 16 + cp, cg2 = 256 + q * 16 + cp;
      float wd1[9], wd2[9];
#pragma unroll
      for (int u = 0; u < 9; ++u) {
        wd1[u] = w_dw[cg1 * 9 + u];
        wd2[u] = w_dw[cg2 * 9 + u];
      }
      float a1[16], a2[16];
      const float bd1 = b_dw[cg1], bd2 = b_dw[cg2];
#pragma unroll
      for (int ox = 0; ox < 16; ++ox) {
        a1[ox] = bd1;
        a2[ox] = bd2;
      }
#pragma unroll
      for (int dy = 0; dy < 3; ++dy) {
        const uint4* rp = (const uint4*)(smem + cp * 1440 + (oy + dy) * 80);
        uint4 r0 = rp[0], r1v = rp[1], r2v = rp[2], r3v = rp[3];
        uint2 r4 = ((const uint2*)rp)[8];
        float e1[18], e2[18];
#define UNP(ii, vv)                \
  {                                \
    unsigned int v_ = (vv);        \
    e1[ii] = bflo(v_);             \
    e2[ii] = bfhi(v_);             \
  }
        UNP(0, r0.x) UNP(1, r0.y) UNP(2, r0.z) UNP(3, r0.w)
        UNP(4, r1v.x) UNP(5, r1v.y) UNP(6, r1v.z) UNP(7, r1v.w)
        UNP(8, r2v.x) UNP(9, r2v.y) UNP(10, r2v.z) UNP(11, r2v.w)
        UNP(12, r3v.x) UNP(13, r3v.y) UNP(14, r3v.z) UNP(15, r3v.w)
        UNP(16, r4.x) UNP(17, r4.y)
#undef UNP
#pragma unroll
        for (int ox = 0; ox < 16; ++ox) {
#pragma unroll
          for (int dx = 0; dx < 3; ++dx) {
            a1[ox] = fmaf(wd1[dy * 3 + dx], e1[ox + dx], a1[ox]);
            a2[ox] = fmaf(wd2[dy * 3 + dx], e2[ox + dx], a2[ox]);
          }
        }
      }
      const int c2 = (q & 1) * 16 + cp;
      unsigned short* G = (unsigned short*)(smem + 23040);
#pragma unroll
      for (int ox = 0; ox < 16; ++ox) {
        float u = a1[ox];
        float g = 0.5f * u * (1.f + erff(u * 0.70710678118654752f)) * a2[ox];
        int px = oy * 16 + ox;
        G[px * 40 + ((c2 >> 3) ^ (px & 3)) * 8 + (c2 & 7)] = f2bf(g);
      }
    }
    __syncthreads();

    // ---- stage C every 2 chunks: y += w_out[:,32] @ G ----
    if (q & 1) {
      const int p = q >> 1;
      short8 cf = *(const short8*)(wsC + ((p * 4 + wave) * 64 + lane) * 8);
      const unsigned short* G = (const unsigned short*)(smem + 23040);
#pragma unroll
      for (int nt = 0; nt < 16; ++nt) {
        int n = nt * 16 + l15;
        short8 bf = *(const short8*)(G + n * 40 + ((lg ^ (n & 3)) * 8));
        accY[nt] = __builtin_amdgcn_mfma_f32_16x16x32_bf16(cf, bf, accY[nt], 0, 0, 0);
      }
    }
  }

  // ---- epilogue ----
  f32x4 bo;
#pragma unroll
  for (int r = 0; r < 4; ++r) bo[r] = b_out[wave * 16 + lg * 4 + r];
#pragma unroll
  for (int nt = 0; nt < 16; ++nt)
#pragma unroll
    for (int r = 0; r < 4; ++r) accY[nt][r] += bo[r];

  if (t == 0) s_flag = 1;
  __syncthreads();
  {
    int ok = 1;
    const float* kc = ws;
#pragma unroll
    for (int j = 0; j < 16; ++j) {
      int idx = t * 16 + j;
      float e = ((idx & 63) == 0) ? 1.f : 0.f;
      ok &= (fabsf(kc[idx] - e) <= 1e-5f) ? 1 : 0;
    }
    if (!ok) s_flag = 0;
  }
  __syncthreads();

  const int o = wave * 16 + lg * 4;
  if (s_flag) {  // identity spectral filter: direct store
#pragma unroll
    for (int nt = 0; nt < 16; ++nt) {
      float* op = out + (((size_t)(b * 64 + o)) * IH + gy0 + nt) * IW + gx0 + l15;
#pragma unroll
      for (int r = 0; r < 4; ++r) op[(size_t)r * IH * IW] = accY[nt][r];
    }
    return;
  }

  // general path: per-patch circular convolution with kc (correct for any filter)
  float* YS = (float*)smem;  // [32][260]
  for (int half = 0; half < 2; ++half) {
    __syncthreads();
    if ((wave >> 1) == half) {
      int c32 = (wave & 1) * 16 + lg * 4;
#pragma unroll
      for (int nt = 0; nt < 16; ++nt)
#pragma unroll
        for (int r = 0; r < 4; ++r) YS[(c32 + r) * 260 + nt * 16 + l15] = accY[nt][r];
    }
    __syncthreads();
    if (t < 128) {
      int o32 = t >> 2, oo = half * 32 + o32, qd = t & 3;
      const float* kp = ws + oo * 64;
      int py0 = (qd >> 1) * 8, px0 = (qd & 1) * 8;
      const float* row = YS + o32 * 260;
      for (int i = 0; i < 8; ++i)
        for (int j = 0; j < 8; ++j) {
          float acc = 0.f;
          for (int a_ = 0; a_ < 8; ++a_)
            for (int b_ = 0; b_ < 8; ++b_)
              acc += kp[a_ * 8 + b_] *
                     row[(py0 + ((i - a_) & 7)) * 16 + px0 + ((j - b_) & 7)];
          out[(((size_t)(b * 64 + oo)) * IH + gy0 + py0 + i) * IW + gx0 + px0 + j] = acc;
        }
    }
  }
}

extern "C" void kernel_launch(void* const* d_in, const int* in_sizes, int n_in,
                              void* d_out, int out_size, void* d_ws, size_t ws_size,
                              hipStream_t stream) {
  const float* x = (const float*)d_in[0];
  const float* w_in = (const float*)d_in[1];
  const float* b_in = (const float*)d_in[2];
  const float* w_dw = (const float*)d_in[3];
  const float* b_dw = (const float*)d_in[4];
  const float* w_out = (const float*)d_in[5];
  const float* b_out = (const float*)d_in[6];
  const float* fftf = (const float*)d_in[7];
  float* out = (float*)d_out;
  float* ws = (float*)d_ws;

  edffn_prep<<<160, 64, 0, stream>>>(fftf, w_in, w_out, ws);
  dim3 grid(IW / TILE, IH / TILE, 4);
  edffn_main<<<grid, 256, 0, stream>>>(x, b_in, w_dw, b_dw, b_out, ws, out);
}